// Round 3
// baseline (99.362 us; speedup 1.0000x reference)
//
#include <hip/hip_runtime.h>
#include <hip/hip_bf16.h>
#include <cstdint>

// Problem: B=8, N=1024, C=256, H=8, D=64.
// out[b,i,o] = sum_{h,d} V[b,i,h,d] * w[b,i,h] * Wout[o,h,d]
// w[b,i,h]   = sum_j exp(S_ij)/d_j ;  S = Q K^T / 8 ; d_j = sum_i exp(S_ij)
// Scale fold: Wq' = Wq * 0.125*log2(e)  =>  exp(S/8) == exp2(Q'K^T).
// Layouts: Qh/Kh/Vh = [b][h][i][d] (head-major, contiguous per (b,h)).
//          Wg2 = [b][h][i]. Wt = [3][n=512][c=256]. Wob = [o=256][k=512].

typedef __attribute__((ext_vector_type(8))) short bf16x8;
typedef __attribute__((ext_vector_type(4))) float f32x4;

#if __has_builtin(__builtin_amdgcn_exp2f)
#define EXP2(x) __builtin_amdgcn_exp2f(x)
#else
#define EXP2(x) exp2f(x)
#endif

static __device__ __forceinline__ uint32_t pk2(float x, float y) {
  union { __hip_bfloat162 h; uint32_t u; } c;
  c.h = __float22bfloat162_rn(float2{x, y});
  return c.u;
}
static __device__ __forceinline__ short cvt1(float f) {
  union { __hip_bfloat16 h; short s; } c;
  c.h = __float2bfloat16(f);
  return c.s;
}

#define MFMA(a, b, c) __builtin_amdgcn_mfma_f32_16x16x32_bf16((a), (b), (c), 0, 0, 0)

// ---------------------------------------------------------------------------
// Kernel 0: weight prep (unchanged from round 2).
// ---------------------------------------------------------------------------
__global__ __launch_bounds__(256) void k_prep(
    const float* __restrict__ Wq, const float* __restrict__ Wk,
    const float* __restrict__ Wv, const float* __restrict__ Wo,
    short* __restrict__ Wt, short* __restrict__ Wob)
{
  const int t = blockIdx.x * 256 + threadIdx.x;
  if (t < 49152) {
    const int m  = t >> 14;
    const int r  = t & 16383;
    const int n  = r >> 5;     // 0..511
    const int c8 = r & 31;     // c = c8*8
    const float* W = (m == 0) ? Wq : (m == 1) ? Wk : Wv;
    const float scale = (m == 0) ? 0.18033688011112042f : 1.0f;
    short tmp[8];
#pragma unroll
    for (int j = 0; j < 8; ++j)
      tmp[j] = cvt1(W[(size_t)(c8 * 8 + j) * 512 + n] * scale);
    *(int4*)&Wt[(size_t)m * 131072 + n * 256 + c8 * 8] = *(int4*)tmp;
  } else {
    const int r  = t - 49152;  // 0..16383
    const int o  = r >> 6;     // 0..255
    const int k8 = r & 63;     // k = k8*8
    const float4 v0 = *(const float4*)(Wo + (size_t)o * 512 + k8 * 8);
    const float4 v1 = *(const float4*)(Wo + (size_t)o * 512 + k8 * 8 + 4);
    uint32_t tmp[4] = {pk2(v0.x, v0.y), pk2(v0.z, v0.w),
                       pk2(v1.x, v1.y), pk2(v1.z, v1.w)};
    *(uint4*)&Wob[(size_t)o * 512 + k8 * 8] = *(uint4*)tmp;
  }
}

// ---------------------------------------------------------------------------
// Kernel 1: fused QKV projection. 512 blocks x 256.
// Decode: groups (mt,b) of 8 nt-blocks co-located per XCD (A-tile L2 reuse).
// Writes head-major Qh/Kh/Vh.
// ---------------------------------------------------------------------------
__global__ __launch_bounds__(256) void k_qkv(
    const float* __restrict__ F, const short* __restrict__ Wt,
    short* __restrict__ Qh, short* __restrict__ Kh, short* __restrict__ Vh)
{
  const int hw   = blockIdx.x;
  const int slot = hw >> 3;
  const int g    = (hw & 7) * 8 + (slot >> 3);  // 0..63 = (mt,b)
  const int h    = slot & 7;                    // head / n-panel
  const int mt   = g & 7;
  const int b    = g >> 3;
  const int n0   = h * 64;
  const int m0   = mt * 128;

  __shared__ short As[128][72];
  __shared__ short Bs[3][64][72];

  const int t  = threadIdx.x;
  const int wv = t >> 6;
  const int l  = t & 63;
  const int lo = l & 15;
  const int hi = l >> 4;

  float4 pa[8];
  int4   pb[6];
  // prefetch k-step 0
#pragma unroll
  for (int it = 0; it < 8; ++it) {
    int idx = t + it * 256, r = idx >> 4, c4 = idx & 15;
    pa[it] = *(const float4*)(F + (size_t)(b * 1024 + m0 + r) * 256 + c4 * 4);
  }
#pragma unroll
  for (int it = 0; it < 6; ++it) {
    int idx = t + it * 256, m = idx >> 9, rem = idx & 511, n = rem >> 3, c8 = rem & 7;
    pb[it] = *(const int4*)(Wt + ((size_t)m * 512 + n0 + n) * 256 + c8 * 8);
  }

  f32x4 acc[3][2][4];
#pragma unroll
  for (int m = 0; m < 3; ++m)
#pragma unroll
    for (int i = 0; i < 2; ++i)
#pragma unroll
      for (int j = 0; j < 4; ++j) acc[m][i][j] = (f32x4){0.f, 0.f, 0.f, 0.f};

  for (int s = 0; s < 4; ++s) {
    if (s) __syncthreads();
    // write staged regs -> LDS (implicit vmcnt wait here)
#pragma unroll
    for (int it = 0; it < 8; ++it) {
      int idx = t + it * 256, r = idx >> 4, c4 = idx & 15;
      uint32_t u[2] = {pk2(pa[it].x, pa[it].y), pk2(pa[it].z, pa[it].w)};
      *(uint2*)&As[r][c4 * 4] = *(uint2*)u;
    }
#pragma unroll
    for (int it = 0; it < 6; ++it) {
      int idx = t + it * 256, m = idx >> 9, rem = idx & 511, n = rem >> 3, c8 = rem & 7;
      *(int4*)&Bs[m][n][c8 * 8] = pb[it];
    }
    __syncthreads();
    // issue next step's loads (in flight during compute)
    if (s < 3) {
      const int k0 = (s + 1) * 64;
#pragma unroll
      for (int it = 0; it < 8; ++it) {
        int idx = t + it * 256, r = idx >> 4, c4 = idx & 15;
        pa[it] = *(const float4*)(F + (size_t)(b * 1024 + m0 + r) * 256 + k0 + c4 * 4);
      }
#pragma unroll
      for (int it = 0; it < 6; ++it) {
        int idx = t + it * 256, m = idx >> 9, rem = idx & 511, n = rem >> 3, c8 = rem & 7;
        pb[it] = *(const int4*)(Wt + ((size_t)m * 512 + n0 + n) * 256 + k0 + c8 * 8);
      }
    }

    bf16x8 a[2][2];
#pragma unroll
    for (int fr = 0; fr < 2; ++fr)
#pragma unroll
      for (int kk = 0; kk < 2; ++kk)
        a[fr][kk] = *(const bf16x8*)&As[wv * 32 + fr * 16 + lo][kk * 32 + hi * 8];
#pragma unroll
    for (int m = 0; m < 3; ++m)
#pragma unroll
      for (int kk = 0; kk < 2; ++kk)
#pragma unroll
        for (int fc = 0; fc < 4; ++fc) {
          bf16x8 bfr = *(const bf16x8*)&Bs[m][fc * 16 + lo][kk * 32 + hi * 8];
#pragma unroll
          for (int fr = 0; fr < 2; ++fr)
            acc[m][fr][fc] = MFMA(a[fr][kk], bfr, acc[m][fr][fc]);
        }
  }

#pragma unroll
  for (int m = 0; m < 3; ++m) {
    short* O = (m == 0) ? Qh : (m == 1) ? Kh : Vh;
#pragma unroll
    for (int fr = 0; fr < 2; ++fr)
#pragma unroll
      for (int fc = 0; fc < 4; ++fc)
#pragma unroll
        for (int r = 0; r < 4; ++r) {
          int i = m0 + wv * 32 + fr * 16 + hi * 4 + r;
          int d = fc * 16 + lo;
          O[((size_t)(b * 8 + h) * 1024 + i) * 64 + d] = cvt1(acc[m][fr][fc][r]);
        }
  }
}

// ---------------------------------------------------------------------------
// Kernel 2: column denominators d_j = sum_i exp2(S'_ij). 512 blocks x 256.
// Block: j-slice 128 (K resident: LDS + per-wave reg frags, 32 j per wave),
// streams all Q in 8 tiles of 128 rows with reg-prefetch.
// ---------------------------------------------------------------------------
__global__ __launch_bounds__(256) void k_colsum(
    const short* __restrict__ Qh, const short* __restrict__ Kh,
    float* __restrict__ Dd)
{
  const int hw   = blockIdx.x;
  const int slot = hw >> 3;
  const int g    = (hw & 7) * 8 + (slot >> 3);  // (b,h): 8 groups per XCD
  const int jb   = slot & 7;
  const int b    = g >> 3;
  const int h    = g & 7;
  const size_t base = (size_t)(b * 8 + h) * 65536;  // 1024*64 elements
  const int j0   = jb * 128;

  __shared__ short Ks[128][72];
  __shared__ short Qs[128][72];

  const int t  = threadIdx.x;
  const int wv = t >> 6;
  const int l  = t & 63;
  const int lo = l & 15;
  const int hi = l >> 4;

  // stage resident K slice (128 x 64)
#pragma unroll
  for (int it = 0; it < 4; ++it) {
    int idx = t + it * 256, r = idx >> 3, c8 = idx & 7;
    *(int4*)&Ks[r][c8 * 8] = *(const int4*)(Kh + base + (size_t)(j0 + r) * 64 + c8 * 8);
  }
  // prefetch Q tile 0
  int4 pq[4];
#pragma unroll
  for (int it = 0; it < 4; ++it) {
    int idx = t + it * 256, r = idx >> 3, c8 = idx & 7;
    pq[it] = *(const int4*)(Qh + base + (size_t)r * 64 + c8 * 8);
  }
  __syncthreads();

  // resident K fragments: 2 j-strips of 16 per wave
  bf16x8 bk[2][2];
#pragma unroll
  for (int js = 0; js < 2; ++js)
#pragma unroll
    for (int kk = 0; kk < 2; ++kk)
      bk[js][kk] = *(const bf16x8*)&Ks[wv * 32 + js * 16 + lo][kk * 32 + hi * 8];

  float cs[2] = {0.f, 0.f};
  for (int tile = 0; tile < 8; ++tile) {
    if (tile) __syncthreads();
#pragma unroll
    for (int it = 0; it < 4; ++it) {
      int idx = t + it * 256, r = idx >> 3, c8 = idx & 7;
      *(int4*)&Qs[r][c8 * 8] = pq[it];
    }
    __syncthreads();
    if (tile < 7) {
#pragma unroll
      for (int it = 0; it < 4; ++it) {
        int idx = t + it * 256, r = idx >> 3, c8 = idx & 7;
        pq[it] = *(const int4*)(Qh + base + (size_t)((tile + 1) * 128 + r) * 64 + c8 * 8);
      }
    }
#pragma unroll
    for (int f = 0; f < 8; ++f) {
      bf16x8 a0 = *(const bf16x8*)&Qs[f * 16 + lo][hi * 8];
      bf16x8 a1 = *(const bf16x8*)&Qs[f * 16 + lo][32 + hi * 8];
#pragma unroll
      for (int js = 0; js < 2; ++js) {
        f32x4 acc = (f32x4){0.f, 0.f, 0.f, 0.f};
        acc = MFMA(a0, bk[js][0], acc);
        acc = MFMA(a1, bk[js][1], acc);
#pragma unroll
        for (int r = 0; r < 4; ++r) cs[js] += EXP2(acc[r]);
      }
    }
  }

#pragma unroll
  for (int js = 0; js < 2; ++js) {
    cs[js] += __shfl_xor(cs[js], 16, 64);
    cs[js] += __shfl_xor(cs[js], 32, 64);
  }
  if (hi == 0) {
    Dd[(size_t)(b * 8 + h) * 1024 + j0 + wv * 32 + lo]      = cs[0];
    Dd[(size_t)(b * 8 + h) * 1024 + j0 + wv * 32 + 16 + lo] = cs[1];
  }
}

// ---------------------------------------------------------------------------
// Kernel 3: w_i = sum_j exp2(S'_ij)/d_j. 512 blocks x 256.
// Block: i-slice 128 (Q resident), streams all K; writes Wg2[b][h][i].
// ---------------------------------------------------------------------------
__global__ __launch_bounds__(256) void k_rowsum(
    const short* __restrict__ Qh, const short* __restrict__ Kh,
    const float* __restrict__ Dd, float* __restrict__ Wg2)
{
  const int hw   = blockIdx.x;
  const int slot = hw >> 3;
  const int g    = (hw & 7) * 8 + (slot >> 3);
  const int ib   = slot & 7;
  const int b    = g >> 3;
  const int h    = g & 7;
  const size_t base = (size_t)(b * 8 + h) * 65536;
  const int i0   = ib * 128;

  __shared__ short Qs[128][72];
  __shared__ short Ks[128][72];
  __shared__ float Rs[1024];

  const int t  = threadIdx.x;
  const int wv = t >> 6;
  const int l  = t & 63;
  const int lo = l & 15;
  const int hi = l >> 4;

  // reciprocal denominators
  {
    const float4 dv = *(const float4*)(Dd + (size_t)(b * 8 + h) * 1024 + t * 4);
    Rs[t * 4 + 0] = __builtin_amdgcn_rcpf(dv.x);
    Rs[t * 4 + 1] = __builtin_amdgcn_rcpf(dv.y);
    Rs[t * 4 + 2] = __builtin_amdgcn_rcpf(dv.z);
    Rs[t * 4 + 3] = __builtin_amdgcn_rcpf(dv.w);
  }
  // stage resident Q slice
#pragma unroll
  for (int it = 0; it < 4; ++it) {
    int idx = t + it * 256, r = idx >> 3, c8 = idx & 7;
    *(int4*)&Qs[r][c8 * 8] = *(const int4*)(Qh + base + (size_t)(i0 + r) * 64 + c8 * 8);
  }
  // prefetch K tile 0
  int4 pk[4];
#pragma unroll
  for (int it = 0; it < 4; ++it) {
    int idx = t + it * 256, r = idx >> 3, c8 = idx & 7;
    pk[it] = *(const int4*)(Kh + base + (size_t)r * 64 + c8 * 8);
  }
  __syncthreads();

  // resident Q fragments: 2 i-strips of 16 per wave
  bf16x8 aq[2][2];
#pragma unroll
  for (int is = 0; is < 2; ++is)
#pragma unroll
    for (int kk = 0; kk < 2; ++kk)
      aq[is][kk] = *(const bf16x8*)&Qs[wv * 32 + is * 16 + lo][kk * 32 + hi * 8];

  float wa[2][4] = {{0.f, 0.f, 0.f, 0.f}, {0.f, 0.f, 0.f, 0.f}};
  for (int tile = 0; tile < 8; ++tile) {
    if (tile) __syncthreads();
#pragma unroll
    for (int it = 0; it < 4; ++it) {
      int idx = t + it * 256, r = idx >> 3, c8 = idx & 7;
      *(int4*)&Ks[r][c8 * 8] = pk[it];
    }
    __syncthreads();
    if (tile < 7) {
#pragma unroll
      for (int it = 0; it < 4; ++it) {
        int idx = t + it * 256, r = idx >> 3, c8 = idx & 7;
        pk[it] = *(const int4*)(Kh + base + (size_t)((tile + 1) * 128 + r) * 64 + c8 * 8);
      }
    }
#pragma unroll
    for (int f = 0; f < 8; ++f) {
      bf16x8 b0 = *(const bf16x8*)&Ks[f * 16 + lo][hi * 8];
      bf16x8 b1 = *(const bf16x8*)&Ks[f * 16 + lo][32 + hi * 8];
      float rj = Rs[tile * 128 + f * 16 + lo];
#pragma unroll
      for (int is = 0; is < 2; ++is) {
        f32x4 acc = (f32x4){0.f, 0.f, 0.f, 0.f};
        acc = MFMA(aq[is][0], b0, acc);
        acc = MFMA(aq[is][1], b1, acc);
#pragma unroll
        for (int r = 0; r < 4; ++r) wa[is][r] = fmaf(EXP2(acc[r]), rj, wa[is][r]);
      }
    }
  }

#pragma unroll
  for (int m = 1; m <= 8; m <<= 1)
#pragma unroll
    for (int is = 0; is < 2; ++is)
#pragma unroll
      for (int r = 0; r < 4; ++r) wa[is][r] += __shfl_xor(wa[is][r], m, 64);

  if (lo == 0) {
#pragma unroll
    for (int is = 0; is < 2; ++is) {
      float4 o = {wa[is][0], wa[is][1], wa[is][2], wa[is][3]};
      *(float4*)&Wg2[(size_t)(b * 8 + h) * 1024 + i0 + wv * 32 + is * 16 + hi * 4] = o;
    }
  }
}

// ---------------------------------------------------------------------------
// Kernel 4: out = (V .* w) @ Wob^T. 512 blocks x 256.
// M-tile 64, N-tile 64, K-step 64 (= one head). Reg-prefetch staging.
// ---------------------------------------------------------------------------
__global__ __launch_bounds__(256) void k_out(
    const short* __restrict__ Vh, const float* __restrict__ Wg2,
    const short* __restrict__ Wob, float* __restrict__ Out)
{
  const int hw   = blockIdx.x;
  const int slot = hw >> 3;
  const int g    = (hw & 7) * 16 + (slot >> 2);  // 0..127 = (mt,b)
  const int nt   = slot & 3;
  const int b    = g >> 4;
  const int mt   = g & 15;
  const int n0   = nt * 64;
  const int m0   = mt * 64;

  __shared__ short As[64][72];
  __shared__ short Bs[64][72];

  const int t  = threadIdx.x;
  const int wv = t >> 6;
  const int l  = t & 63;
  const int lo = l & 15;
  const int hi = l >> 4;

  int4  pv[2], pbb[2];
  float pw[2];
#pragma unroll
  for (int it = 0; it < 2; ++it) {
    int idx = t + it * 256, r = idx >> 3, c8 = idx & 7;
    pv[it]  = *(const int4*)(Vh + ((size_t)(b * 8 + 0) * 1024 + m0 + r) * 64 + c8 * 8);
    pw[it]  = Wg2[(size_t)(b * 8 + 0) * 1024 + m0 + r];
    int n = r;
    pbb[it] = *(const int4*)(Wob + (size_t)(n0 + n) * 512 + 0 * 64 + c8 * 8);
  }

  f32x4 acc[4];
#pragma unroll
  for (int j = 0; j < 4; ++j) acc[j] = (f32x4){0.f, 0.f, 0.f, 0.f};

  for (int s = 0; s < 8; ++s) {
    if (s) __syncthreads();
#pragma unroll
    for (int it = 0; it < 2; ++it) {
      int idx = t + it * 256, r = idx >> 3, c8 = idx & 7;
      uint32_t* u = (uint32_t*)&pv[it];
      float ws = pw[it];
      uint32_t o[4];
#pragma unroll
      for (int j = 0; j < 4; ++j) {
        float f0 = __uint_as_float(u[j] << 16) * ws;
        float f1 = __uint_as_float(u[j] & 0xffff0000u) * ws;
        o[j] = pk2(f0, f1);
      }
      *(uint4*)&As[r][c8 * 8] = *(uint4*)o;
      *(int4*)&Bs[r][c8 * 8]  = pbb[it];
    }
    __syncthreads();
    if (s < 7) {
#pragma unroll
      for (int it = 0; it < 2; ++it) {
        int idx = t + it * 256, r = idx >> 3, c8 = idx & 7;
        pv[it]  = *(const int4*)(Vh + ((size_t)(b * 8 + s + 1) * 1024 + m0 + r) * 64 + c8 * 8);
        pw[it]  = Wg2[(size_t)(b * 8 + s + 1) * 1024 + m0 + r];
        pbb[it] = *(const int4*)(Wob + (size_t)(n0 + r) * 512 + (s + 1) * 64 + c8 * 8);
      }
    }

#pragma unroll
    for (int kk = 0; kk < 2; ++kk) {
      bf16x8 a = *(const bf16x8*)&As[wv * 16 + lo][kk * 32 + hi * 8];
#pragma unroll
      for (int fc = 0; fc < 4; ++fc) {
        bf16x8 bfr = *(const bf16x8*)&Bs[fc * 16 + lo][kk * 32 + hi * 8];
        acc[fc] = MFMA(a, bfr, acc[fc]);
      }
    }
  }

#pragma unroll
  for (int fc = 0; fc < 4; ++fc)
#pragma unroll
    for (int r = 0; r < 4; ++r) {
      int i = m0 + wv * 16 + hi * 4 + r;
      int o = n0 + fc * 16 + lo;
      Out[(size_t)(b * 1024 + i) * 256 + o] = acc[fc][r];
    }
}

// ---------------------------------------------------------------------------
extern "C" void kernel_launch(void* const* d_in, const int* in_sizes, int n_in,
                              void* d_out, int out_size, void* d_ws, size_t ws_size,
                              hipStream_t stream) {
  const float* F  = (const float*)d_in[0];
  const float* Wq = (const float*)d_in[1];
  const float* Wk = (const float*)d_in[2];
  const float* Wv = (const float*)d_in[3];
  const float* Wo = (const float*)d_in[4];
  float* out = (float*)d_out;

  char* ws = (char*)d_ws;
  short* Qh  = (short*)(ws);                                     // 8 MB bf16
  short* Kh  = (short*)(ws + (size_t)(8  << 20));                // 8 MB
  short* Vh  = (short*)(ws + (size_t)(16 << 20));                // 8 MB
  float* Dd  = (float*)(ws + (size_t)(24 << 20));                // 256 KB
  float* Wg2 = (float*)(ws + (size_t)(24 << 20) + (256 << 10));  // 256 KB
  short* Wt  = (short*)(ws + (size_t)(24 << 20) + (512 << 10));  // 768 KB
  short* Wob = (short*)(ws + (size_t)(24 << 20) + (1280 << 10)); // 256 KB

  k_prep  <<<dim3(256), 256, 0, stream>>>(Wq, Wk, Wv, Wo, Wt, Wob);
  k_qkv   <<<dim3(512), 256, 0, stream>>>(F, Wt, Qh, Kh, Vh);
  k_colsum<<<dim3(512), 256, 0, stream>>>(Qh, Kh, Dd);
  k_rowsum<<<dim3(512), 256, 0, stream>>>(Qh, Kh, Dd, Wg2);
  k_out   <<<dim3(512), 256, 0, stream>>>(Vh, Wg2, Wob, out);
}